// Round 20
// baseline (93.527 us; speedup 1.0000x reference)
//
#include <hip/hip_runtime.h>

#define NN 65536
#define FH 128
#define FO 16
#define NE (NN * 16)
#define EPB 4096   // edges per bucketA block (= per-block tmp region)
#define BCAP 8192  // per-bucket padded capacity in evw16 (mean 4096, sd 62)

typedef unsigned short u16x8 __attribute__((ext_vector_type(8)));
typedef unsigned short u16x4 __attribute__((ext_vector_type(4)));
typedef float f32x4 __attribute__((ext_vector_type(4)));
typedef short s16x8 __attribute__((ext_vector_type(8)));

__device__ inline float b2f(unsigned short u) {
    union { unsigned int i; float f; } x;
    x.i = ((unsigned int)u) << 16;
    return x.f;
}
__device__ inline unsigned short f2bf(float f) {
    union { float f; unsigned int i; } x;
    x.f = f;
    unsigned int r = x.i + 0x7fff + ((x.i >> 16) & 1);  // RNE
    return (unsigned short)(r >> 16);
}

// ============ bucketA (blocks 0..255) + w1cvt (blocks 256..263) ============
// bucketA: per-block LDS counting sort by u>>8, fully coalesced writes
__global__ __launch_bounds__(256) void bucketA(const int* __restrict__ eu,
                                               const int* __restrict__ ev,
                                               unsigned int* __restrict__ tmp,
                                               int* __restrict__ cnts,
                                               int* __restrict__ offs,
                                               const float* __restrict__ W1,
                                               unsigned short* __restrict__ w1t) {
    const int tid = threadIdx.x;
    const int blk = blockIdx.x;
    if (blk >= 256) {
        // w1cvt: w1t[c][k] = bf16(W1[k][c])
        const int gid = (blk - 256) * 256 + tid;  // 2048 chunks
        const int c = gid >> 4;
        const int k0 = (gid & 15) * 8;
        u16x8 o;
#pragma unroll
        for (int j = 0; j < 8; ++j) o[j] = f2bf(W1[(size_t)(k0 + j) * 128 + c]);
        *(u16x8*)&w1t[(size_t)c * 128 + k0] = o;
        return;
    }
    __shared__ int lhist[256];
    __shared__ int lscan[256];
    __shared__ int lcur[256];
    __shared__ unsigned int lsorted[EPB];  // 16KB
    lhist[tid] = 0;
    __syncthreads();
    const int e0 = blk * EPB;
    int us[16], vs[16];
#pragma unroll
    for (int k = 0; k < 16; ++k) {
        int e = e0 + k * 256 + tid;
        us[k] = eu[e];
        vs[k] = ev[e];
        atomicAdd(&lhist[us[k] >> 8], 1);
    }
    __syncthreads();
    const int c = lhist[tid];
    lscan[tid] = c;
    __syncthreads();
    for (int off = 1; off < 256; off <<= 1) {
        int v = (tid >= off) ? lscan[tid - off] : 0;
        __syncthreads();
        lscan[tid] += v;
        __syncthreads();
    }
    const int start = lscan[tid] - c;  // exclusive
    lcur[tid] = start;
    cnts[blk * 256 + tid] = c;   // coalesced
    offs[blk * 256 + tid] = start;
    __syncthreads();
#pragma unroll
    for (int k = 0; k < 16; ++k) {
        int bin = us[k] >> 8;
        int pos = atomicAdd(&lcur[bin], 1);
        lsorted[pos] = (((unsigned int)(us[k] & 255)) << 16) | (unsigned int)vs[k];
    }
    __syncthreads();
    for (int i = tid; i < EPB; i += 256) {
        tmp[(size_t)blk * EPB + i] = lsorted[i];  // coalesced full lines
    }
}

// ============ bucketB: coalesced run-gather (binsearch) + counting sort ============
__global__ __launch_bounds__(256) void bucketB(const unsigned int* __restrict__ tmp,
                                               const int* __restrict__ cnts,
                                               const int* __restrict__ offs,
                                               unsigned short* __restrict__ evw16,
                                               int* __restrict__ row_start,
                                               int* __restrict__ deg,
                                               float* __restrict__ isd) {
    __shared__ int lcnt[256];
    __shared__ int lscan[256];
    __shared__ int lcur[256];
    __shared__ int lrunend[256];  // inclusive scan of run sizes (preserved)
    __shared__ int lgsrc[256];    // global tmp base of each run
    __shared__ int stot;
    __shared__ unsigned int lrec[BCAP];     // 32KB
    __shared__ unsigned short lbuf[BCAP];   // 16KB
    const int b = blockIdx.x;
    const int tid = threadIdx.x;
    // thread t owns block-run t for this bucket
    const int ct = cnts[tid * 256 + b];
    const int roff = offs[tid * 256 + b];
    lscan[tid] = ct;
    __syncthreads();
    for (int off = 1; off < 256; off <<= 1) {
        int v = (tid >= off) ? lscan[tid - off] : 0;
        __syncthreads();
        lscan[tid] += v;
        __syncthreads();
    }
    lrunend[tid] = lscan[tid];
    lgsrc[tid] = tid * EPB + roff;
    if (tid == 255) stot = lscan[255];
    __syncthreads();
    const int total = stot;
    // coalesced gather: consecutive i -> mostly same run -> consecutive tmp addrs
    for (int i = tid; i < total; i += 256) {
        int lo = 0, hi = 255;
        while (lo < hi) {
            int mid = (lo + hi) >> 1;
            if (lrunend[mid] > i) hi = mid; else lo = mid + 1;
        }
        int rb = (lo == 0) ? 0 : lrunend[lo - 1];
        lrec[i] = tmp[(size_t)lgsrc[lo] + (i - rb)];
    }
    lcnt[tid] = 0;
    __syncthreads();
    for (int i = tid; i < total; i += 256) {
        atomicAdd(&lcnt[lrec[i] >> 16], 1);
    }
    __syncthreads();
    const int c = lcnt[tid];
    lscan[tid] = c;
    __syncthreads();
    for (int off = 1; off < 256; off <<= 1) {
        int v = (tid >= off) ? lscan[tid - off] : 0;
        __syncthreads();
        lscan[tid] += v;
        __syncthreads();
    }
    const int myStart = lscan[tid] - c;  // exclusive
    lcur[tid] = myStart;
    const int node = b * 256 + tid;
    row_start[node] = b * BCAP + myStart;
    deg[node] = c;
    isd[node] = (c > 0) ? (1.0f / sqrtf((float)c)) : 0.0f;
    __syncthreads();
    for (int i = tid; i < total; i += 256) {
        unsigned int rec = lrec[i];
        int off = atomicAdd(&lcur[rec >> 16], 1);
        lbuf[off] = (unsigned short)(rec & 0xFFFFu);
    }
    __syncthreads();
    for (int i = tid; i < total; i += 256) {
        evw16[(size_t)b * BCAP + i] = lbuf[i];
    }
}

// ============ GEMM1 (MFMA): t1s = bf16(isd[row] * (x @ W1)) ============
__global__ __launch_bounds__(256) void gemm1_mfma(const float* __restrict__ x,
                                                  const unsigned short* __restrict__ w1t,
                                                  const float* __restrict__ isd,
                                                  unsigned short* __restrict__ t1s) {
    __shared__ unsigned short wsT[128][136];  // wsT[c][k] = bf16(W1[k][c])
    const int tid = threadIdx.x;
    const int row0 = blockIdx.x * 64;
    for (int i = tid; i < 2048; i += 256) {
        int cc = i >> 4;
        int k0 = (i & 15) * 8;
        *(u16x8*)&wsT[cc][k0] = *(const u16x8*)&w1t[(size_t)cc * 128 + k0];
    }
    const int lane = tid & 63;
    const int w = tid >> 6;
    const int ar = row0 + w * 16 + (lane & 15);  // A row (global)
    const int k0 = (lane >> 4) * 8;
    s16x8 afrag[4];
#pragma unroll
    for (int kk = 0; kk < 4; ++kk) {
        float4 va = *(const float4*)&x[(size_t)ar * 128 + kk * 32 + k0];
        float4 vb = *(const float4*)&x[(size_t)ar * 128 + kk * 32 + k0 + 4];
        u16x8 t;
        t[0] = f2bf(va.x); t[1] = f2bf(va.y); t[2] = f2bf(va.z); t[3] = f2bf(va.w);
        t[4] = f2bf(vb.x); t[5] = f2bf(vb.y); t[6] = f2bf(vb.z); t[7] = f2bf(vb.w);
        afrag[kk] = *(s16x8*)&t;
    }
    __syncthreads();
    f32x4 acc[8];
#pragma unroll
    for (int n = 0; n < 8; ++n) acc[n] = (f32x4){0.f, 0.f, 0.f, 0.f};
#pragma unroll
    for (int n = 0; n < 8; ++n) {
        const int bc = n * 16 + (lane & 15);
#pragma unroll
        for (int kk = 0; kk < 4; ++kk) {
            s16x8 bfrag = *(const s16x8*)&wsT[bc][kk * 32 + k0];
            acc[n] = __builtin_amdgcn_mfma_f32_16x16x32_bf16(afrag[kk], bfrag, acc[n], 0, 0, 0);
        }
    }
    const int orow = row0 + w * 16 + (lane >> 4) * 4;
    const float s0 = isd[orow + 0];
    const float s1 = isd[orow + 1];
    const float s2 = isd[orow + 2];
    const float s3 = isd[orow + 3];
#pragma unroll
    for (int n = 0; n < 8; ++n) {
        const int col = n * 16 + (lane & 15);
        t1s[(size_t)(orow + 0) * 128 + col] = f2bf(s0 * acc[n][0]);
        t1s[(size_t)(orow + 1) * 128 + col] = f2bf(s1 * acc[n][1]);
        t1s[(size_t)(orow + 2) * 128 + col] = f2bf(s2 * acc[n][2]);
        t1s[(size_t)(orow + 3) * 128 + col] = f2bf(s3 * acc[n][3]);
    }
}

// ============ FUSED layer-1 aggregate + relu + GEMM2, LDS-staged indices ============
__global__ __launch_bounds__(256) void fused_agg_gemm2(const int* __restrict__ row_start,
                                                       const int* __restrict__ deg,
                                                       const unsigned short* __restrict__ evw16,
                                                       const float* __restrict__ isd,
                                                       const unsigned short* __restrict__ src,
                                                       const float* __restrict__ W2,
                                                       unsigned short* __restrict__ t2s) {
    __shared__ unsigned short hs[16][136];   // bf16 h tile
    __shared__ unsigned short w2T[16][136];  // bf16 W2^T
    __shared__ unsigned short lidx[1024];    // staged edge indices
    const int tid = threadIdx.x;
    const int n0 = blockIdx.x * 16;
    const int eb = row_start[n0];
    const int ee = row_start[n0 + 15] + deg[n0 + 15];
    const int cnt = ee - eb;
    for (int i = tid; i < cnt; i += 256) lidx[i] = evw16[eb + i];
    for (int i = tid; i < 128 * 16; i += 256) {
        int k = i >> 4, cc = i & 15;
        w2T[cc][k] = f2bf(W2[i]);
    }
    const int slot = tid >> 4;
    const int node = n0 + slot;
    const int c0 = (tid & 15) * 8;
    const int rs = row_start[node];
    const int d = deg[node];
    const int ib = rs - eb;
    const float s = isd[node];
    __syncthreads();
    float acc[8] = {};
    int p = 0;
    for (; p + 8 <= d; p += 8) {
        int v0 = lidx[ib + p + 0];
        int v1 = lidx[ib + p + 1];
        int v2 = lidx[ib + p + 2];
        int v3 = lidx[ib + p + 3];
        int v4 = lidx[ib + p + 4];
        int v5 = lidx[ib + p + 5];
        int v6 = lidx[ib + p + 6];
        int v7 = lidx[ib + p + 7];
        u16x8 a0 = *(const u16x8*)&src[(size_t)v0 * 128 + c0];
        u16x8 a1 = *(const u16x8*)&src[(size_t)v1 * 128 + c0];
        u16x8 a2 = *(const u16x8*)&src[(size_t)v2 * 128 + c0];
        u16x8 a3 = *(const u16x8*)&src[(size_t)v3 * 128 + c0];
        u16x8 a4 = *(const u16x8*)&src[(size_t)v4 * 128 + c0];
        u16x8 a5 = *(const u16x8*)&src[(size_t)v5 * 128 + c0];
        u16x8 a6 = *(const u16x8*)&src[(size_t)v6 * 128 + c0];
        u16x8 a7 = *(const u16x8*)&src[(size_t)v7 * 128 + c0];
#pragma unroll
        for (int j = 0; j < 8; ++j)
            acc[j] += ((b2f(a0[j]) + b2f(a1[j])) + (b2f(a2[j]) + b2f(a3[j]))) +
                      ((b2f(a4[j]) + b2f(a5[j])) + (b2f(a6[j]) + b2f(a7[j])));
    }
    for (; p + 2 <= d; p += 2) {
        int v0 = lidx[ib + p + 0];
        int v1 = lidx[ib + p + 1];
        u16x8 a0 = *(const u16x8*)&src[(size_t)v0 * 128 + c0];
        u16x8 a1 = *(const u16x8*)&src[(size_t)v1 * 128 + c0];
#pragma unroll
        for (int j = 0; j < 8; ++j) acc[j] += b2f(a0[j]) + b2f(a1[j]);
    }
    if (p < d) {
        int v0 = lidx[ib + p];
        u16x8 a = *(const u16x8*)&src[(size_t)v0 * 128 + c0];
#pragma unroll
        for (int j = 0; j < 8; ++j) acc[j] += b2f(a[j]);
    }
    u16x8 o;
#pragma unroll
    for (int j = 0; j < 8; ++j) o[j] = f2bf(fmaxf(s * acc[j], 0.f));
    *(u16x8*)&hs[slot][c0] = o;
    __syncthreads();
    const int tx = tid & 15;
    float acc2 = 0.f;
#pragma unroll
    for (int k = 0; k < 128; k += 8) {
        u16x8 hv = *(const u16x8*)&hs[slot][k];
        u16x8 wv = *(const u16x8*)&w2T[tx][k];
#pragma unroll
        for (int j = 0; j < 8; ++j) acc2 += b2f(hv[j]) * b2f(wv[j]);
    }
    t2s[(size_t)node * 16 + tx] = f2bf(s * acc2);
}

// ============ gather F=16 (bf16 t2s), unroll-8: out[n] = isd[n] * sum t2s[v] ============
__global__ __launch_bounds__(256) void spmm_gather16f(const int* __restrict__ row_start,
                                                      const int* __restrict__ deg,
                                                      const unsigned short* __restrict__ evw16,
                                                      const float* __restrict__ isd,
                                                      const unsigned short* __restrict__ t2s,
                                                      float* __restrict__ out) {
    __shared__ unsigned short lidx[2048];
    const int tid = threadIdx.x;
    const int n0 = blockIdx.x * 64;
    const int eb = row_start[n0];
    const int ee = row_start[n0 + 63] + deg[n0 + 63];
    const int cnt = ee - eb;
    for (int i = tid; i < cnt; i += 256) lidx[i] = evw16[eb + i];
    const int node = n0 + (tid >> 2);
    const int j = (tid & 3) * 4;
    const int rs = row_start[node];
    const int d = deg[node];
    const int ib = rs - eb;
    const float s = isd[node];
    __syncthreads();
    float acc0 = 0.f, acc1 = 0.f, acc2 = 0.f, acc3 = 0.f;
    int p = 0;
    for (; p + 8 <= d; p += 8) {
        u16x4 a0 = *(const u16x4*)&t2s[(size_t)lidx[ib + p + 0] * 16 + j];
        u16x4 a1 = *(const u16x4*)&t2s[(size_t)lidx[ib + p + 1] * 16 + j];
        u16x4 a2 = *(const u16x4*)&t2s[(size_t)lidx[ib + p + 2] * 16 + j];
        u16x4 a3 = *(const u16x4*)&t2s[(size_t)lidx[ib + p + 3] * 16 + j];
        u16x4 a4 = *(const u16x4*)&t2s[(size_t)lidx[ib + p + 4] * 16 + j];
        u16x4 a5 = *(const u16x4*)&t2s[(size_t)lidx[ib + p + 5] * 16 + j];
        u16x4 a6 = *(const u16x4*)&t2s[(size_t)lidx[ib + p + 6] * 16 + j];
        u16x4 a7 = *(const u16x4*)&t2s[(size_t)lidx[ib + p + 7] * 16 + j];
        acc0 += ((b2f(a0[0]) + b2f(a1[0])) + (b2f(a2[0]) + b2f(a3[0]))) +
                ((b2f(a4[0]) + b2f(a5[0])) + (b2f(a6[0]) + b2f(a7[0])));
        acc1 += ((b2f(a0[1]) + b2f(a1[1])) + (b2f(a2[1]) + b2f(a3[1]))) +
                ((b2f(a4[1]) + b2f(a5[1])) + (b2f(a6[1]) + b2f(a7[1])));
        acc2 += ((b2f(a0[2]) + b2f(a1[2])) + (b2f(a2[2]) + b2f(a3[2]))) +
                ((b2f(a4[2]) + b2f(a5[2])) + (b2f(a6[2]) + b2f(a7[2])));
        acc3 += ((b2f(a0[3]) + b2f(a1[3])) + (b2f(a2[3]) + b2f(a3[3]))) +
                ((b2f(a4[3]) + b2f(a5[3])) + (b2f(a6[3]) + b2f(a7[3])));
    }
    for (; p < d; ++p) {
        u16x4 a = *(const u16x4*)&t2s[(size_t)lidx[ib + p] * 16 + j];
        acc0 += b2f(a[0]);
        acc1 += b2f(a[1]);
        acc2 += b2f(a[2]);
        acc3 += b2f(a[3]);
    }
    float4 o;
    o.x = s * acc0;
    o.y = s * acc1;
    o.z = s * acc2;
    o.w = s * acc3;
    *(float4*)&out[(size_t)node * 16 + j] = o;
}

extern "C" void kernel_launch(void* const* d_in, const int* in_sizes, int n_in,
                              void* d_out, int out_size, void* d_ws, size_t ws_size,
                              hipStream_t stream) {
    const float* x  = (const float*)d_in[0];
    const int*   eu = (const int*)d_in[1];
    const int*   ev = (const int*)d_in[2];
    // d_in[3] (edge_weight) unused: recomputed separably from degrees
    const float* W1 = (const float*)d_in[4];
    const float* W2 = (const float*)d_in[5];
    float* out = (float*)d_out;

    // workspace layout (16B-aligned carve-outs)
    char* p = (char*)d_ws;
    int* row_start        = (int*)p;            p += (size_t)NN * 4;            // 256KB
    int* deg              = (int*)p;            p += (size_t)NN * 4;            // 256KB
    float* isd            = (float*)p;          p += (size_t)NN * 4;            // 256KB
    int* cnts             = (int*)p;            p += (size_t)256 * 256 * 4;     // 256KB
    int* offs             = (int*)p;            p += (size_t)256 * 256 * 4;     // 256KB
    unsigned int* tmp     = (unsigned int*)p;   p += (size_t)NE * 4;            // 4MB
    unsigned short* evw16 = (unsigned short*)p; p += (size_t)256 * BCAP * 2;    // 4MB
    unsigned short* w1t   = (unsigned short*)p; p += (size_t)FH * FH * 2;       // 32KB
    unsigned short* t1s   = (unsigned short*)p; p += (size_t)NN * FH * 2;       // 16MB
    unsigned short* t2s   = (unsigned short*)p;                                 // 2MB

    // CSR build (bucketA blocks 0..255) + W1 bf16-transpose (blocks 256..263)
    bucketA<<<NE / EPB + 8, 256, 0, stream>>>(eu, ev, tmp, cnts, offs, W1, w1t);
    bucketB<<<256, 256, 0, stream>>>(tmp, cnts, offs, evw16, row_start, deg, isd);

    // layer 1: t1s = bf16(isd * (x @ W1))
    gemm1_mfma<<<NN / 64, 256, 0, stream>>>(x, w1t, isd, t1s);

    // fused: h = relu(isd * gather(t1s)) ; t2s = bf16(isd * (h @ W2))
    fused_agg_gemm2<<<NN / 16, 256, 0, stream>>>(row_start, deg, evw16, isd, t1s, W2, t2s);

    // out = isd * gather(t2s)
    spmm_gather16f<<<NN / 64, 256, 0, stream>>>(row_start, deg, evw16, isd, t2s, out);
}

// Round 21
// 83.036 us; speedup vs baseline: 1.1263x; 1.1263x over previous
//
#include <hip/hip_runtime.h>

#define NN 65536
#define FH 128
#define FO 16
#define NE (NN * 16)
#define EPB 4096   // edges per bucketA block (= per-block tmp region)
#define BCAP 8192  // per-bucket padded capacity in evw16 (mean 4096, sd 62)

typedef unsigned short u16x8 __attribute__((ext_vector_type(8)));
typedef unsigned short u16x4 __attribute__((ext_vector_type(4)));
typedef float f32x4 __attribute__((ext_vector_type(4)));
typedef short s16x8 __attribute__((ext_vector_type(8)));

__device__ inline float b2f(unsigned short u) {
    union { unsigned int i; float f; } x;
    x.i = ((unsigned int)u) << 16;
    return x.f;
}
__device__ inline unsigned short f2bf(float f) {
    union { float f; unsigned int i; } x;
    x.f = f;
    unsigned int r = x.i + 0x7fff + ((x.i >> 16) & 1);  // RNE
    return (unsigned short)(r >> 16);
}

// ============ bucketA (blocks 0..255) + w1cvt (blocks 256..263) ============
// bucketA: per-block LDS counting sort by u>>8, fully coalesced writes
__global__ __launch_bounds__(256) void bucketA(const int* __restrict__ eu,
                                               const int* __restrict__ ev,
                                               unsigned int* __restrict__ tmp,
                                               int* __restrict__ cnts,
                                               int* __restrict__ offs,
                                               const float* __restrict__ W1,
                                               unsigned short* __restrict__ w1t) {
    const int tid = threadIdx.x;
    const int blk = blockIdx.x;
    if (blk >= 256) {
        // w1cvt: w1t[c][k] = bf16(W1[k][c])
        const int gid = (blk - 256) * 256 + tid;  // 2048 chunks
        const int c = gid >> 4;
        const int k0 = (gid & 15) * 8;
        u16x8 o;
#pragma unroll
        for (int j = 0; j < 8; ++j) o[j] = f2bf(W1[(size_t)(k0 + j) * 128 + c]);
        *(u16x8*)&w1t[(size_t)c * 128 + k0] = o;
        return;
    }
    __shared__ int lhist[256];
    __shared__ int lscan[256];
    __shared__ int lcur[256];
    __shared__ unsigned int lsorted[EPB];  // 16KB
    lhist[tid] = 0;
    __syncthreads();
    const int e0 = blk * EPB;
    int us[16], vs[16];
#pragma unroll
    for (int k = 0; k < 16; ++k) {
        int e = e0 + k * 256 + tid;
        us[k] = eu[e];
        vs[k] = ev[e];
        atomicAdd(&lhist[us[k] >> 8], 1);
    }
    __syncthreads();
    const int c = lhist[tid];
    lscan[tid] = c;
    __syncthreads();
    for (int off = 1; off < 256; off <<= 1) {
        int v = (tid >= off) ? lscan[tid - off] : 0;
        __syncthreads();
        lscan[tid] += v;
        __syncthreads();
    }
    const int start = lscan[tid] - c;  // exclusive
    lcur[tid] = start;
    cnts[blk * 256 + tid] = c;   // coalesced
    offs[blk * 256 + tid] = start;
    __syncthreads();
#pragma unroll
    for (int k = 0; k < 16; ++k) {
        int bin = us[k] >> 8;
        int pos = atomicAdd(&lcur[bin], 1);
        lsorted[pos] = (((unsigned int)(us[k] & 255)) << 16) | (unsigned int)vs[k];
    }
    __syncthreads();
    for (int i = tid; i < EPB; i += 256) {
        tmp[(size_t)blk * EPB + i] = lsorted[i];  // coalesced full lines
    }
}

// ============ bucketB: serial run-copy gather (pipelined) + counting sort ============
__global__ __launch_bounds__(256) void bucketB(const unsigned int* __restrict__ tmp,
                                               const int* __restrict__ cnts,
                                               const int* __restrict__ offs,
                                               unsigned short* __restrict__ evw16,
                                               int* __restrict__ row_start,
                                               int* __restrict__ deg,
                                               float* __restrict__ isd) {
    __shared__ int lcnt[256];
    __shared__ int lscan[256];
    __shared__ int lcur[256];
    __shared__ int stot;
    __shared__ unsigned int lrec[BCAP];     // 32KB
    __shared__ unsigned short lbuf[BCAP];   // 16KB
    const int b = blockIdx.x;
    const int tid = threadIdx.x;
    // thread t owns block-run t for this bucket
    const int ct = cnts[tid * 256 + b];
    const int roff = offs[tid * 256 + b];
    lscan[tid] = ct;
    __syncthreads();
    for (int off = 1; off < 256; off <<= 1) {
        int v = (tid >= off) ? lscan[tid - off] : 0;
        __syncthreads();
        lscan[tid] += v;
        __syncthreads();
    }
    const int rbase = lscan[tid] - ct;
    if (tid == 255) stot = lscan[255];
    __syncthreads();
    const int total = stot;
    const unsigned int* src = &tmp[(size_t)tid * EPB + roff];
    for (int k = 0; k < ct; ++k) lrec[rbase + k] = src[k];
    lcnt[tid] = 0;
    __syncthreads();
    for (int i = tid; i < total; i += 256) {
        atomicAdd(&lcnt[lrec[i] >> 16], 1);
    }
    __syncthreads();
    const int c = lcnt[tid];
    lscan[tid] = c;
    __syncthreads();
    for (int off = 1; off < 256; off <<= 1) {
        int v = (tid >= off) ? lscan[tid - off] : 0;
        __syncthreads();
        lscan[tid] += v;
        __syncthreads();
    }
    const int myStart = lscan[tid] - c;  // exclusive
    lcur[tid] = myStart;
    const int node = b * 256 + tid;
    row_start[node] = b * BCAP + myStart;
    deg[node] = c;
    isd[node] = (c > 0) ? (1.0f / sqrtf((float)c)) : 0.0f;
    __syncthreads();
    for (int i = tid; i < total; i += 256) {
        unsigned int rec = lrec[i];
        int off = atomicAdd(&lcur[rec >> 16], 1);
        lbuf[off] = (unsigned short)(rec & 0xFFFFu);
    }
    __syncthreads();
    for (int i = tid; i < total; i += 256) {
        evw16[(size_t)b * BCAP + i] = lbuf[i];
    }
}

// ============ GEMM1 (MFMA): t1s = bf16(isd[row] * (x @ W1)) ============
__global__ __launch_bounds__(256) void gemm1_mfma(const float* __restrict__ x,
                                                  const unsigned short* __restrict__ w1t,
                                                  const float* __restrict__ isd,
                                                  unsigned short* __restrict__ t1s) {
    __shared__ unsigned short wsT[128][136];  // wsT[c][k] = bf16(W1[k][c])
    const int tid = threadIdx.x;
    const int row0 = blockIdx.x * 64;
    for (int i = tid; i < 2048; i += 256) {
        int cc = i >> 4;
        int k0 = (i & 15) * 8;
        *(u16x8*)&wsT[cc][k0] = *(const u16x8*)&w1t[(size_t)cc * 128 + k0];
    }
    const int lane = tid & 63;
    const int w = tid >> 6;
    const int ar = row0 + w * 16 + (lane & 15);  // A row (global)
    const int k0 = (lane >> 4) * 8;
    s16x8 afrag[4];
#pragma unroll
    for (int kk = 0; kk < 4; ++kk) {
        float4 va = *(const float4*)&x[(size_t)ar * 128 + kk * 32 + k0];
        float4 vb = *(const float4*)&x[(size_t)ar * 128 + kk * 32 + k0 + 4];
        u16x8 t;
        t[0] = f2bf(va.x); t[1] = f2bf(va.y); t[2] = f2bf(va.z); t[3] = f2bf(va.w);
        t[4] = f2bf(vb.x); t[5] = f2bf(vb.y); t[6] = f2bf(vb.z); t[7] = f2bf(vb.w);
        afrag[kk] = *(s16x8*)&t;
    }
    __syncthreads();
    f32x4 acc[8];
#pragma unroll
    for (int n = 0; n < 8; ++n) acc[n] = (f32x4){0.f, 0.f, 0.f, 0.f};
#pragma unroll
    for (int n = 0; n < 8; ++n) {
        const int bc = n * 16 + (lane & 15);
#pragma unroll
        for (int kk = 0; kk < 4; ++kk) {
            s16x8 bfrag = *(const s16x8*)&wsT[bc][kk * 32 + k0];
            acc[n] = __builtin_amdgcn_mfma_f32_16x16x32_bf16(afrag[kk], bfrag, acc[n], 0, 0, 0);
        }
    }
    const int orow = row0 + w * 16 + (lane >> 4) * 4;
    const float s0 = isd[orow + 0];
    const float s1 = isd[orow + 1];
    const float s2 = isd[orow + 2];
    const float s3 = isd[orow + 3];
#pragma unroll
    for (int n = 0; n < 8; ++n) {
        const int col = n * 16 + (lane & 15);
        t1s[(size_t)(orow + 0) * 128 + col] = f2bf(s0 * acc[n][0]);
        t1s[(size_t)(orow + 1) * 128 + col] = f2bf(s1 * acc[n][1]);
        t1s[(size_t)(orow + 2) * 128 + col] = f2bf(s2 * acc[n][2]);
        t1s[(size_t)(orow + 3) * 128 + col] = f2bf(s3 * acc[n][3]);
    }
}

// ============ FUSED layer-1 aggregate + relu + GEMM2, LDS-staged indices ============
__global__ __launch_bounds__(256) void fused_agg_gemm2(const int* __restrict__ row_start,
                                                       const int* __restrict__ deg,
                                                       const unsigned short* __restrict__ evw16,
                                                       const float* __restrict__ isd,
                                                       const unsigned short* __restrict__ src,
                                                       const float* __restrict__ W2,
                                                       unsigned short* __restrict__ t2s) {
    __shared__ unsigned short hs[16][136];   // bf16 h tile
    __shared__ unsigned short w2T[16][136];  // bf16 W2^T
    __shared__ unsigned short lidx[1024];    // staged edge indices
    const int tid = threadIdx.x;
    const int n0 = blockIdx.x * 16;
    const int eb = row_start[n0];
    const int ee = row_start[n0 + 15] + deg[n0 + 15];
    const int cnt = ee - eb;
    for (int i = tid; i < cnt; i += 256) lidx[i] = evw16[eb + i];
    for (int i = tid; i < 128 * 16; i += 256) {
        int k = i >> 4, cc = i & 15;
        w2T[cc][k] = f2bf(W2[i]);
    }
    const int slot = tid >> 4;
    const int node = n0 + slot;
    const int c0 = (tid & 15) * 8;
    const int rs = row_start[node];
    const int d = deg[node];
    const int ib = rs - eb;
    const float s = isd[node];
    __syncthreads();
    float acc[8] = {};
    int p = 0;
    for (; p + 8 <= d; p += 8) {
        int v0 = lidx[ib + p + 0];
        int v1 = lidx[ib + p + 1];
        int v2 = lidx[ib + p + 2];
        int v3 = lidx[ib + p + 3];
        int v4 = lidx[ib + p + 4];
        int v5 = lidx[ib + p + 5];
        int v6 = lidx[ib + p + 6];
        int v7 = lidx[ib + p + 7];
        u16x8 a0 = *(const u16x8*)&src[(size_t)v0 * 128 + c0];
        u16x8 a1 = *(const u16x8*)&src[(size_t)v1 * 128 + c0];
        u16x8 a2 = *(const u16x8*)&src[(size_t)v2 * 128 + c0];
        u16x8 a3 = *(const u16x8*)&src[(size_t)v3 * 128 + c0];
        u16x8 a4 = *(const u16x8*)&src[(size_t)v4 * 128 + c0];
        u16x8 a5 = *(const u16x8*)&src[(size_t)v5 * 128 + c0];
        u16x8 a6 = *(const u16x8*)&src[(size_t)v6 * 128 + c0];
        u16x8 a7 = *(const u16x8*)&src[(size_t)v7 * 128 + c0];
#pragma unroll
        for (int j = 0; j < 8; ++j)
            acc[j] += ((b2f(a0[j]) + b2f(a1[j])) + (b2f(a2[j]) + b2f(a3[j]))) +
                      ((b2f(a4[j]) + b2f(a5[j])) + (b2f(a6[j]) + b2f(a7[j])));
    }
    for (; p + 2 <= d; p += 2) {
        int v0 = lidx[ib + p + 0];
        int v1 = lidx[ib + p + 1];
        u16x8 a0 = *(const u16x8*)&src[(size_t)v0 * 128 + c0];
        u16x8 a1 = *(const u16x8*)&src[(size_t)v1 * 128 + c0];
#pragma unroll
        for (int j = 0; j < 8; ++j) acc[j] += b2f(a0[j]) + b2f(a1[j]);
    }
    if (p < d) {
        int v0 = lidx[ib + p];
        u16x8 a = *(const u16x8*)&src[(size_t)v0 * 128 + c0];
#pragma unroll
        for (int j = 0; j < 8; ++j) acc[j] += b2f(a[j]);
    }
    u16x8 o;
#pragma unroll
    for (int j = 0; j < 8; ++j) o[j] = f2bf(fmaxf(s * acc[j], 0.f));
    *(u16x8*)&hs[slot][c0] = o;
    __syncthreads();
    const int tx = tid & 15;
    float acc2 = 0.f;
#pragma unroll
    for (int k = 0; k < 128; k += 8) {
        u16x8 hv = *(const u16x8*)&hs[slot][k];
        u16x8 wv = *(const u16x8*)&w2T[tx][k];
#pragma unroll
        for (int j = 0; j < 8; ++j) acc2 += b2f(hv[j]) * b2f(wv[j]);
    }
    t2s[(size_t)node * 16 + tx] = f2bf(s * acc2);
}

// ============ gather F=16 (bf16 t2s), unroll-8: out[n] = isd[n] * sum t2s[v] ============
__global__ __launch_bounds__(256) void spmm_gather16f(const int* __restrict__ row_start,
                                                      const int* __restrict__ deg,
                                                      const unsigned short* __restrict__ evw16,
                                                      const float* __restrict__ isd,
                                                      const unsigned short* __restrict__ t2s,
                                                      float* __restrict__ out) {
    __shared__ unsigned short lidx[2048];
    const int tid = threadIdx.x;
    const int n0 = blockIdx.x * 64;
    const int eb = row_start[n0];
    const int ee = row_start[n0 + 63] + deg[n0 + 63];
    const int cnt = ee - eb;
    for (int i = tid; i < cnt; i += 256) lidx[i] = evw16[eb + i];
    const int node = n0 + (tid >> 2);
    const int j = (tid & 3) * 4;
    const int rs = row_start[node];
    const int d = deg[node];
    const int ib = rs - eb;
    const float s = isd[node];
    __syncthreads();
    float acc0 = 0.f, acc1 = 0.f, acc2 = 0.f, acc3 = 0.f;
    int p = 0;
    for (; p + 8 <= d; p += 8) {
        u16x4 a0 = *(const u16x4*)&t2s[(size_t)lidx[ib + p + 0] * 16 + j];
        u16x4 a1 = *(const u16x4*)&t2s[(size_t)lidx[ib + p + 1] * 16 + j];
        u16x4 a2 = *(const u16x4*)&t2s[(size_t)lidx[ib + p + 2] * 16 + j];
        u16x4 a3 = *(const u16x4*)&t2s[(size_t)lidx[ib + p + 3] * 16 + j];
        u16x4 a4 = *(const u16x4*)&t2s[(size_t)lidx[ib + p + 4] * 16 + j];
        u16x4 a5 = *(const u16x4*)&t2s[(size_t)lidx[ib + p + 5] * 16 + j];
        u16x4 a6 = *(const u16x4*)&t2s[(size_t)lidx[ib + p + 6] * 16 + j];
        u16x4 a7 = *(const u16x4*)&t2s[(size_t)lidx[ib + p + 7] * 16 + j];
        acc0 += ((b2f(a0[0]) + b2f(a1[0])) + (b2f(a2[0]) + b2f(a3[0]))) +
                ((b2f(a4[0]) + b2f(a5[0])) + (b2f(a6[0]) + b2f(a7[0])));
        acc1 += ((b2f(a0[1]) + b2f(a1[1])) + (b2f(a2[1]) + b2f(a3[1]))) +
                ((b2f(a4[1]) + b2f(a5[1])) + (b2f(a6[1]) + b2f(a7[1])));
        acc2 += ((b2f(a0[2]) + b2f(a1[2])) + (b2f(a2[2]) + b2f(a3[2]))) +
                ((b2f(a4[2]) + b2f(a5[2])) + (b2f(a6[2]) + b2f(a7[2])));
        acc3 += ((b2f(a0[3]) + b2f(a1[3])) + (b2f(a2[3]) + b2f(a3[3]))) +
                ((b2f(a4[3]) + b2f(a5[3])) + (b2f(a6[3]) + b2f(a7[3])));
    }
    for (; p < d; ++p) {
        u16x4 a = *(const u16x4*)&t2s[(size_t)lidx[ib + p] * 16 + j];
        acc0 += b2f(a[0]);
        acc1 += b2f(a[1]);
        acc2 += b2f(a[2]);
        acc3 += b2f(a[3]);
    }
    float4 o;
    o.x = s * acc0;
    o.y = s * acc1;
    o.z = s * acc2;
    o.w = s * acc3;
    *(float4*)&out[(size_t)node * 16 + j] = o;
}

extern "C" void kernel_launch(void* const* d_in, const int* in_sizes, int n_in,
                              void* d_out, int out_size, void* d_ws, size_t ws_size,
                              hipStream_t stream) {
    const float* x  = (const float*)d_in[0];
    const int*   eu = (const int*)d_in[1];
    const int*   ev = (const int*)d_in[2];
    // d_in[3] (edge_weight) unused: recomputed separably from degrees
    const float* W1 = (const float*)d_in[4];
    const float* W2 = (const float*)d_in[5];
    float* out = (float*)d_out;

    // workspace layout (16B-aligned carve-outs)
    char* p = (char*)d_ws;
    int* row_start        = (int*)p;            p += (size_t)NN * 4;            // 256KB
    int* deg              = (int*)p;            p += (size_t)NN * 4;            // 256KB
    float* isd            = (float*)p;          p += (size_t)NN * 4;            // 256KB
    int* cnts             = (int*)p;            p += (size_t)256 * 256 * 4;     // 256KB
    int* offs             = (int*)p;            p += (size_t)256 * 256 * 4;     // 256KB
    unsigned int* tmp     = (unsigned int*)p;   p += (size_t)NE * 4;            // 4MB
    unsigned short* evw16 = (unsigned short*)p; p += (size_t)256 * BCAP * 2;    // 4MB
    unsigned short* w1t   = (unsigned short*)p; p += (size_t)FH * FH * 2;       // 32KB
    unsigned short* t1s   = (unsigned short*)p; p += (size_t)NN * FH * 2;       // 16MB
    unsigned short* t2s   = (unsigned short*)p;                                 // 2MB

    // CSR build (bucketA blocks 0..255) + W1 bf16-transpose (blocks 256..263)
    bucketA<<<NE / EPB + 8, 256, 0, stream>>>(eu, ev, tmp, cnts, offs, W1, w1t);
    bucketB<<<256, 256, 0, stream>>>(tmp, cnts, offs, evw16, row_start, deg, isd);

    // layer 1: t1s = bf16(isd * (x @ W1))
    gemm1_mfma<<<NN / 64, 256, 0, stream>>>(x, w1t, isd, t1s);

    // fused: h = relu(isd * gather(t1s)) ; t2s = bf16(isd * (h @ W2))
    fused_agg_gemm2<<<NN / 16, 256, 0, stream>>>(row_start, deg, evw16, isd, t1s, W2, t2s);

    // out = isd * gather(t2s)
    spmm_gather16f<<<NN / 64, 256, 0, stream>>>(row_start, deg, evw16, isd, t2s, out);
}

// Round 22
// 79.790 us; speedup vs baseline: 1.1722x; 1.0407x over previous
//
#include <hip/hip_runtime.h>

#define NN 65536
#define FH 128
#define FO 16
#define NE (NN * 16)
#define EPB 4096   // edges per bucketA block (= per-block tmp region)
#define BCAP 8192  // per-bucket padded capacity in evw16 (mean 4096, sd 62)

typedef unsigned short u16x8 __attribute__((ext_vector_type(8)));
typedef unsigned short u16x4 __attribute__((ext_vector_type(4)));
typedef float f32x4 __attribute__((ext_vector_type(4)));
typedef short s16x8 __attribute__((ext_vector_type(8)));
typedef signed char s8x8 __attribute__((ext_vector_type(8)));

__device__ inline float b2f(unsigned short u) {
    union { unsigned int i; float f; } x;
    x.i = ((unsigned int)u) << 16;
    return x.f;
}
__device__ inline unsigned short f2bf(float f) {
    union { float f; unsigned int i; } x;
    x.f = f;
    unsigned int r = x.i + 0x7fff + ((x.i >> 16) & 1);  // RNE
    return (unsigned short)(r >> 16);
}

// ============ bucketA (blocks 0..255) + w1cvt (blocks 256..263) ============
__global__ __launch_bounds__(256) void bucketA(const int* __restrict__ eu,
                                               const int* __restrict__ ev,
                                               unsigned int* __restrict__ tmp,
                                               int* __restrict__ cnts,
                                               int* __restrict__ offs,
                                               const float* __restrict__ W1,
                                               unsigned short* __restrict__ w1t) {
    const int tid = threadIdx.x;
    const int blk = blockIdx.x;
    if (blk >= 256) {
        const int gid = (blk - 256) * 256 + tid;  // 2048 chunks
        const int c = gid >> 4;
        const int k0 = (gid & 15) * 8;
        u16x8 o;
#pragma unroll
        for (int j = 0; j < 8; ++j) o[j] = f2bf(W1[(size_t)(k0 + j) * 128 + c]);
        *(u16x8*)&w1t[(size_t)c * 128 + k0] = o;
        return;
    }
    __shared__ int lhist[256];
    __shared__ int lscan[256];
    __shared__ int lcur[256];
    __shared__ unsigned int lsorted[EPB];  // 16KB
    lhist[tid] = 0;
    __syncthreads();
    const int e0 = blk * EPB;
    int us[16], vs[16];
#pragma unroll
    for (int k = 0; k < 16; ++k) {
        int e = e0 + k * 256 + tid;
        us[k] = eu[e];
        vs[k] = ev[e];
        atomicAdd(&lhist[us[k] >> 8], 1);
    }
    __syncthreads();
    const int c = lhist[tid];
    lscan[tid] = c;
    __syncthreads();
    for (int off = 1; off < 256; off <<= 1) {
        int v = (tid >= off) ? lscan[tid - off] : 0;
        __syncthreads();
        lscan[tid] += v;
        __syncthreads();
    }
    const int start = lscan[tid] - c;  // exclusive
    lcur[tid] = start;
    cnts[blk * 256 + tid] = c;
    offs[blk * 256 + tid] = start;
    __syncthreads();
#pragma unroll
    for (int k = 0; k < 16; ++k) {
        int bin = us[k] >> 8;
        int pos = atomicAdd(&lcur[bin], 1);
        lsorted[pos] = (((unsigned int)(us[k] & 255)) << 16) | (unsigned int)vs[k];
    }
    __syncthreads();
    for (int i = tid; i < EPB; i += 256) {
        tmp[(size_t)blk * EPB + i] = lsorted[i];
    }
}

// ============ bucketB: serial run-copy gather + counting sort ============
__global__ __launch_bounds__(256) void bucketB(const unsigned int* __restrict__ tmp,
                                               const int* __restrict__ cnts,
                                               const int* __restrict__ offs,
                                               unsigned short* __restrict__ evw16,
                                               int* __restrict__ row_start,
                                               int* __restrict__ deg,
                                               float* __restrict__ isd) {
    __shared__ int lcnt[256];
    __shared__ int lscan[256];
    __shared__ int lcur[256];
    __shared__ int stot;
    __shared__ unsigned int lrec[BCAP];     // 32KB
    __shared__ unsigned short lbuf[BCAP];   // 16KB
    const int b = blockIdx.x;
    const int tid = threadIdx.x;
    const int ct = cnts[tid * 256 + b];
    const int roff = offs[tid * 256 + b];
    lscan[tid] = ct;
    __syncthreads();
    for (int off = 1; off < 256; off <<= 1) {
        int v = (tid >= off) ? lscan[tid - off] : 0;
        __syncthreads();
        lscan[tid] += v;
        __syncthreads();
    }
    const int rbase = lscan[tid] - ct;
    if (tid == 255) stot = lscan[255];
    __syncthreads();
    const int total = stot;
    const unsigned int* src = &tmp[(size_t)tid * EPB + roff];
    for (int k = 0; k < ct; ++k) lrec[rbase + k] = src[k];
    lcnt[tid] = 0;
    __syncthreads();
    for (int i = tid; i < total; i += 256) {
        atomicAdd(&lcnt[lrec[i] >> 16], 1);
    }
    __syncthreads();
    const int c = lcnt[tid];
    lscan[tid] = c;
    __syncthreads();
    for (int off = 1; off < 256; off <<= 1) {
        int v = (tid >= off) ? lscan[tid - off] : 0;
        __syncthreads();
        lscan[tid] += v;
        __syncthreads();
    }
    const int myStart = lscan[tid] - c;  // exclusive
    lcur[tid] = myStart;
    const int node = b * 256 + tid;
    row_start[node] = b * BCAP + myStart;
    deg[node] = c;
    isd[node] = (c > 0) ? (1.0f / sqrtf((float)c)) : 0.0f;
    __syncthreads();
    for (int i = tid; i < total; i += 256) {
        unsigned int rec = lrec[i];
        int off = atomicAdd(&lcur[rec >> 16], 1);
        lbuf[off] = (unsigned short)(rec & 0xFFFFu);
    }
    __syncthreads();
    for (int i = tid; i < total; i += 256) {
        evw16[(size_t)b * BCAP + i] = lbuf[i];
    }
}

// ============ GEMM1 (MFMA): t1q = int8-rowscale(isd[row] * (x @ W1)) ============
// q = rint(acc * 127/rowmax); scales[row] = isd*rowmax/127
__global__ __launch_bounds__(256) void gemm1_mfma(const float* __restrict__ x,
                                                  const unsigned short* __restrict__ w1t,
                                                  const float* __restrict__ isd,
                                                  signed char* __restrict__ t1q,
                                                  float* __restrict__ scales) {
    __shared__ unsigned short wsT[128][136];  // wsT[c][k] = bf16(W1[k][c])
    const int tid = threadIdx.x;
    const int row0 = blockIdx.x * 64;
    for (int i = tid; i < 2048; i += 256) {
        int cc = i >> 4;
        int k0 = (i & 15) * 8;
        *(u16x8*)&wsT[cc][k0] = *(const u16x8*)&w1t[(size_t)cc * 128 + k0];
    }
    const int lane = tid & 63;
    const int w = tid >> 6;
    const int ar = row0 + w * 16 + (lane & 15);  // A row (global)
    const int k0 = (lane >> 4) * 8;
    s16x8 afrag[4];
#pragma unroll
    for (int kk = 0; kk < 4; ++kk) {
        float4 va = *(const float4*)&x[(size_t)ar * 128 + kk * 32 + k0];
        float4 vb = *(const float4*)&x[(size_t)ar * 128 + kk * 32 + k0 + 4];
        u16x8 t;
        t[0] = f2bf(va.x); t[1] = f2bf(va.y); t[2] = f2bf(va.z); t[3] = f2bf(va.w);
        t[4] = f2bf(vb.x); t[5] = f2bf(vb.y); t[6] = f2bf(vb.z); t[7] = f2bf(vb.w);
        afrag[kk] = *(s16x8*)&t;
    }
    __syncthreads();
    f32x4 acc[8];
#pragma unroll
    for (int n = 0; n < 8; ++n) acc[n] = (f32x4){0.f, 0.f, 0.f, 0.f};
#pragma unroll
    for (int n = 0; n < 8; ++n) {
        const int bc = n * 16 + (lane & 15);
#pragma unroll
        for (int kk = 0; kk < 4; ++kk) {
            s16x8 bfrag = *(const s16x8*)&wsT[bc][kk * 32 + k0];
            acc[n] = __builtin_amdgcn_mfma_f32_16x16x32_bf16(afrag[kk], bfrag, acc[n], 0, 0, 0);
        }
    }
    const int orow = row0 + w * 16 + (lane >> 4) * 4;
#pragma unroll
    for (int r = 0; r < 4; ++r) {
        // rowmax over the 16 lanes of this row group
        float m = 0.f;
#pragma unroll
        for (int n = 0; n < 8; ++n) m = fmaxf(m, fabsf(acc[n][r]));
        m = fmaxf(m, __shfl_xor(m, 1));
        m = fmaxf(m, __shfl_xor(m, 2));
        m = fmaxf(m, __shfl_xor(m, 4));
        m = fmaxf(m, __shfl_xor(m, 8));
        const float inv = (m > 0.f) ? (127.0f / m) : 0.f;
        const int row = orow + r;
#pragma unroll
        for (int n = 0; n < 8; ++n) {
            float q = rintf(acc[n][r] * inv);
            q = fminf(fmaxf(q, -127.f), 127.f);
            t1q[(size_t)row * 128 + n * 16 + (lane & 15)] = (signed char)(int)q;
        }
        if ((lane & 15) == 0) scales[row] = isd[row] * m * (1.0f / 127.0f);
    }
}

// ============ FUSED aggregate(int8) + relu + GEMM2, LDS-staged indices ============
__global__ __launch_bounds__(256) void fused_agg_gemm2(const int* __restrict__ row_start,
                                                       const int* __restrict__ deg,
                                                       const unsigned short* __restrict__ evw16,
                                                       const float* __restrict__ isd,
                                                       const signed char* __restrict__ src,
                                                       const float* __restrict__ scales,
                                                       const float* __restrict__ W2,
                                                       unsigned short* __restrict__ t2s) {
    __shared__ unsigned short hs[16][136];   // bf16 h tile
    __shared__ unsigned short w2T[16][136];  // bf16 W2^T
    __shared__ unsigned short lidx[1024];    // staged edge indices
    const int tid = threadIdx.x;
    const int n0 = blockIdx.x * 16;
    const int eb = row_start[n0];
    const int ee = row_start[n0 + 15] + deg[n0 + 15];
    const int cnt = ee - eb;
    for (int i = tid; i < cnt; i += 256) lidx[i] = evw16[eb + i];
    for (int i = tid; i < 128 * 16; i += 256) {
        int k = i >> 4, cc = i & 15;
        w2T[cc][k] = f2bf(W2[i]);
    }
    const int slot = tid >> 4;
    const int node = n0 + slot;
    const int c0 = (tid & 15) * 8;
    const int rs = row_start[node];
    const int d = deg[node];
    const int ib = rs - eb;
    const float s = isd[node];
    __syncthreads();
    float acc[8] = {};
    int p = 0;
    for (; p + 8 <= d; p += 8) {
        int v0 = lidx[ib + p + 0];
        int v1 = lidx[ib + p + 1];
        int v2 = lidx[ib + p + 2];
        int v3 = lidx[ib + p + 3];
        int v4 = lidx[ib + p + 4];
        int v5 = lidx[ib + p + 5];
        int v6 = lidx[ib + p + 6];
        int v7 = lidx[ib + p + 7];
        float sc0 = scales[v0], sc1 = scales[v1], sc2 = scales[v2], sc3 = scales[v3];
        float sc4 = scales[v4], sc5 = scales[v5], sc6 = scales[v6], sc7 = scales[v7];
        s8x8 a0 = *(const s8x8*)&src[(size_t)v0 * 128 + c0];
        s8x8 a1 = *(const s8x8*)&src[(size_t)v1 * 128 + c0];
        s8x8 a2 = *(const s8x8*)&src[(size_t)v2 * 128 + c0];
        s8x8 a3 = *(const s8x8*)&src[(size_t)v3 * 128 + c0];
        s8x8 a4 = *(const s8x8*)&src[(size_t)v4 * 128 + c0];
        s8x8 a5 = *(const s8x8*)&src[(size_t)v5 * 128 + c0];
        s8x8 a6 = *(const s8x8*)&src[(size_t)v6 * 128 + c0];
        s8x8 a7 = *(const s8x8*)&src[(size_t)v7 * 128 + c0];
#pragma unroll
        for (int j = 0; j < 8; ++j) {
            acc[j] += sc0 * (float)a0[j] + sc1 * (float)a1[j] +
                      sc2 * (float)a2[j] + sc3 * (float)a3[j] +
                      sc4 * (float)a4[j] + sc5 * (float)a5[j] +
                      sc6 * (float)a6[j] + sc7 * (float)a7[j];
        }
    }
    for (; p + 2 <= d; p += 2) {
        int v0 = lidx[ib + p + 0];
        int v1 = lidx[ib + p + 1];
        float sc0 = scales[v0], sc1 = scales[v1];
        s8x8 a0 = *(const s8x8*)&src[(size_t)v0 * 128 + c0];
        s8x8 a1 = *(const s8x8*)&src[(size_t)v1 * 128 + c0];
#pragma unroll
        for (int j = 0; j < 8; ++j) acc[j] += sc0 * (float)a0[j] + sc1 * (float)a1[j];
    }
    if (p < d) {
        int v0 = lidx[ib + p];
        float sc0 = scales[v0];
        s8x8 a = *(const s8x8*)&src[(size_t)v0 * 128 + c0];
#pragma unroll
        for (int j = 0; j < 8; ++j) acc[j] += sc0 * (float)a[j];
    }
    u16x8 o;
#pragma unroll
    for (int j = 0; j < 8; ++j) o[j] = f2bf(fmaxf(s * acc[j], 0.f));
    *(u16x8*)&hs[slot][c0] = o;
    __syncthreads();
    const int tx = tid & 15;
    float acc2 = 0.f;
#pragma unroll
    for (int k = 0; k < 128; k += 8) {
        u16x8 hv = *(const u16x8*)&hs[slot][k];
        u16x8 wv = *(const u16x8*)&w2T[tx][k];
#pragma unroll
        for (int j = 0; j < 8; ++j) acc2 += b2f(hv[j]) * b2f(wv[j]);
    }
    t2s[(size_t)node * 16 + tx] = f2bf(s * acc2);
}

// ============ gather F=16 (bf16 t2s), unroll-8 ============
__global__ __launch_bounds__(256) void spmm_gather16f(const int* __restrict__ row_start,
                                                      const int* __restrict__ deg,
                                                      const unsigned short* __restrict__ evw16,
                                                      const float* __restrict__ isd,
                                                      const unsigned short* __restrict__ t2s,
                                                      float* __restrict__ out) {
    __shared__ unsigned short lidx[2048];
    const int tid = threadIdx.x;
    const int n0 = blockIdx.x * 64;
    const int eb = row_start[n0];
    const int ee = row_start[n0 + 63] + deg[n0 + 63];
    const int cnt = ee - eb;
    for (int i = tid; i < cnt; i += 256) lidx[i] = evw16[eb + i];
    const int node = n0 + (tid >> 2);
    const int j = (tid & 3) * 4;
    const int rs = row_start[node];
    const int d = deg[node];
    const int ib = rs - eb;
    const float s = isd[node];
    __syncthreads();
    float acc0 = 0.f, acc1 = 0.f, acc2 = 0.f, acc3 = 0.f;
    int p = 0;
    for (; p + 8 <= d; p += 8) {
        u16x4 a0 = *(const u16x4*)&t2s[(size_t)lidx[ib + p + 0] * 16 + j];
        u16x4 a1 = *(const u16x4*)&t2s[(size_t)lidx[ib + p + 1] * 16 + j];
        u16x4 a2 = *(const u16x4*)&t2s[(size_t)lidx[ib + p + 2] * 16 + j];
        u16x4 a3 = *(const u16x4*)&t2s[(size_t)lidx[ib + p + 3] * 16 + j];
        u16x4 a4 = *(const u16x4*)&t2s[(size_t)lidx[ib + p + 4] * 16 + j];
        u16x4 a5 = *(const u16x4*)&t2s[(size_t)lidx[ib + p + 5] * 16 + j];
        u16x4 a6 = *(const u16x4*)&t2s[(size_t)lidx[ib + p + 6] * 16 + j];
        u16x4 a7 = *(const u16x4*)&t2s[(size_t)lidx[ib + p + 7] * 16 + j];
        acc0 += ((b2f(a0[0]) + b2f(a1[0])) + (b2f(a2[0]) + b2f(a3[0]))) +
                ((b2f(a4[0]) + b2f(a5[0])) + (b2f(a6[0]) + b2f(a7[0])));
        acc1 += ((b2f(a0[1]) + b2f(a1[1])) + (b2f(a2[1]) + b2f(a3[1]))) +
                ((b2f(a4[1]) + b2f(a5[1])) + (b2f(a6[1]) + b2f(a7[1])));
        acc2 += ((b2f(a0[2]) + b2f(a1[2])) + (b2f(a2[2]) + b2f(a3[2]))) +
                ((b2f(a4[2]) + b2f(a5[2])) + (b2f(a6[2]) + b2f(a7[2])));
        acc3 += ((b2f(a0[3]) + b2f(a1[3])) + (b2f(a2[3]) + b2f(a3[3]))) +
                ((b2f(a4[3]) + b2f(a5[3])) + (b2f(a6[3]) + b2f(a7[3])));
    }
    for (; p < d; ++p) {
        u16x4 a = *(const u16x4*)&t2s[(size_t)lidx[ib + p] * 16 + j];
        acc0 += b2f(a[0]);
        acc1 += b2f(a[1]);
        acc2 += b2f(a[2]);
        acc3 += b2f(a[3]);
    }
    float4 o;
    o.x = s * acc0;
    o.y = s * acc1;
    o.z = s * acc2;
    o.w = s * acc3;
    *(float4*)&out[(size_t)node * 16 + j] = o;
}

extern "C" void kernel_launch(void* const* d_in, const int* in_sizes, int n_in,
                              void* d_out, int out_size, void* d_ws, size_t ws_size,
                              hipStream_t stream) {
    const float* x  = (const float*)d_in[0];
    const int*   eu = (const int*)d_in[1];
    const int*   ev = (const int*)d_in[2];
    // d_in[3] (edge_weight) unused: recomputed separably from degrees
    const float* W1 = (const float*)d_in[4];
    const float* W2 = (const float*)d_in[5];
    float* out = (float*)d_out;

    // workspace layout (16B-aligned carve-outs)
    char* p = (char*)d_ws;
    int* row_start        = (int*)p;            p += (size_t)NN * 4;            // 256KB
    int* deg              = (int*)p;            p += (size_t)NN * 4;            // 256KB
    float* isd            = (float*)p;          p += (size_t)NN * 4;            // 256KB
    float* scales         = (float*)p;          p += (size_t)NN * 4;            // 256KB
    int* cnts             = (int*)p;            p += (size_t)256 * 256 * 4;     // 256KB
    int* offs             = (int*)p;            p += (size_t)256 * 256 * 4;     // 256KB
    unsigned int* tmp     = (unsigned int*)p;   p += (size_t)NE * 4;            // 4MB
    unsigned short* evw16 = (unsigned short*)p; p += (size_t)256 * BCAP * 2;    // 4MB
    unsigned short* w1t   = (unsigned short*)p; p += (size_t)FH * FH * 2;       // 32KB
    signed char* t1q      = (signed char*)p;    p += (size_t)NN * FH;           // 8MB
    unsigned short* t2s   = (unsigned short*)p;                                 // 2MB

    // CSR build (bucketA blocks 0..255) + W1 bf16-transpose (blocks 256..263)
    bucketA<<<NE / EPB + 8, 256, 0, stream>>>(eu, ev, tmp, cnts, offs, W1, w1t);
    bucketB<<<256, 256, 0, stream>>>(tmp, cnts, offs, evw16, row_start, deg, isd);

    // layer 1: t1q = int8-rowscale(isd * (x @ W1)), scales[row]
    gemm1_mfma<<<NN / 64, 256, 0, stream>>>(x, w1t, isd, t1q, scales);

    // fused: h = relu(isd * sum sc_v * q_v) ; t2s = bf16(isd * (h @ W2))
    fused_agg_gemm2<<<NN / 16, 256, 0, stream>>>(row_start, deg, evw16, isd, t1q, scales, W2, t2s);

    // out = isd * gather(t2s)
    spmm_gather16f<<<NN / 64, 256, 0, stream>>>(row_start, deg, evw16, isd, t2s, out);
}